// Round 6
// baseline (111.154 us; speedup 1.0000x reference)
//
#include <hip/hip_runtime.h>
#include <hip/hip_bf16.h>

// Fused causal attention, S=2048 B=2 H=16 D=128, sbhd, fp32 in/out, bf16 MFMA.
// Round 6: KVBLK=32 + QBLK=64 -> 32KB LDS/block -> 4 blocks/CU (16 waves/CU),
// grid 1024 all co-resident, per-CU-uniform qt permutation, 32-reg staging
// (pipeline fits under the 128-VGPR cap), fragment-linear conflict-free LDS.

#define DDIM    128
#define ROWSTR  4096          // B*H*D element stride along s/t
#define QBLK    64
#define KVBLK   32
#define NQT     32            // 2048 / QBLK
#define QSCALE  0.1275174190023967f   // (1/sqrt(128)) * log2(e)

typedef __attribute__((ext_vector_type(4))) float f32x4;
typedef __attribute__((ext_vector_type(8))) short s16x8;
typedef __attribute__((ext_vector_type(2))) unsigned u32x2;

__device__ inline unsigned pk2bf(float a, float b) {
    union { __hip_bfloat162 h; unsigned u; } cv;
    cv.h = __float22bfloat162_rn(float2{a, b});
    return cv.u;
}

// LDS: per buffer 16KB = K region (8 chunks of 1KB, f = 4m+kk) + V region
// (8 chunks of 1KB, f = db). Chunk slot sigma(r,g,f) =
// (r ^ ((g^phi)&3) ^ ((psi ^ (r>>3))<<2)) + 16g, phi=(f>>1)&3, psi=f&1.
// Reads: ds_read_b128 at rbase[f] + f*1024 (full-chunk coverage -> conflict-
// free for any bijection; single base VGPR + immediate offset).

__device__ inline int sigma_slot(int r, int g, int f) {
    int phi = (f >> 1) & 3, psi = f & 1;
    return (r ^ ((g ^ phi) & 3) ^ ((psi ^ (r >> 3)) << 2)) + 16 * g;
}

__global__ __launch_bounds__(256, 4)
void fattn_kernel(const float* __restrict__ q, const float* __restrict__ k,
                  const float* __restrict__ v, float* __restrict__ out)
{
    __shared__ char lds[2][16384];   // [buf][ K 8KB | V 8KB ]

    const int tid = threadIdx.x;
    const int w = tid >> 6, l = tid & 63, g = l >> 4, lr = l & 15;
    const int bid = blockIdx.x;
    const int bh = bid & 31;          // same-head blocks share an XCD (32%8==0)
    const int j  = bid >> 5;          // 0..31
    // per-CU-uniform qt permutation: CU hosts {j, j+8, j+16, j+24} ->
    // qts {g8, 15-g8, 16+g8, 31-g8}; sum(2qt+2) = 132 for every CU.
    const int g8 = j & 7, mem = j >> 3;
    const int qt = 8 * mem + ((mem & 1) ? (7 - g8) : g8);

    const float* qbh = q + bh * DDIM;
    const float* kbh = k + bh * DDIM;
    const float* vbh = v + bh * DDIM;

    // ---- 8 read bases (per f), computed once
    int rbase[8];
#pragma unroll
    for (int f = 0; f < 8; ++f) rbase[f] = sigma_slot(lr, g, f) * 16;

    // staging maps
    const int krow0 = tid >> 4;          // K: r (0..15), rows krow0, krow0+16
    const int kc    = tid & 15;          // K: d cols 8*kc..; kk=kc>>2, g'=kc&3
    const int kk2   = kc >> 2, kg = kc & 3;
    const int vq4   = tid & 31;          // V: d quad (dd = 4*vq4+jj)
    const int vc    = tid >> 5;          // V: (g,u) of kv group
    const int vg    = vc & 3, vu = vc >> 2;

    f32x4 kreg[4], vreg[4];

    auto prefetch = [&](int kv0) {
        const float* kp = kbh + (size_t)(kv0 + krow0) * ROWSTR + kc * 8;
        kreg[0] = *(const f32x4*)kp;
        kreg[1] = *(const f32x4*)(kp + 4);
        kreg[2] = *(const f32x4*)(kp + (size_t)16 * ROWSTR);
        kreg[3] = *(const f32x4*)(kp + (size_t)16 * ROWSTR + 4);
        const float* vp = vbh + (size_t)(kv0 + 16 * vu + 4 * vg) * ROWSTR + vq4 * 4;
#pragma unroll
        for (int i = 0; i < 4; ++i)
            vreg[i] = *(const f32x4*)(vp + (size_t)i * ROWSTR);
    };

    auto stage = [&](char* base) {
#pragma unroll
        for (int m = 0; m < 2; ++m) {
            int f = 4 * m + kk2;
            s16x8 t; unsigned* tu = (unsigned*)&t;
            tu[0] = pk2bf(kreg[2 * m][0],     kreg[2 * m][1]);
            tu[1] = pk2bf(kreg[2 * m][2],     kreg[2 * m][3]);
            tu[2] = pk2bf(kreg[2 * m + 1][0], kreg[2 * m + 1][1]);
            tu[3] = pk2bf(kreg[2 * m + 1][2], kreg[2 * m + 1][3]);
            *(s16x8*)(base + f * 1024 + sigma_slot(krow0, kg, f) * 16) = t;
        }
#pragma unroll
        for (int jj = 0; jj < 4; ++jj) {
            int dd = 4 * vq4 + jj;
            int f = vq4 >> 2;             // = dd>>4
            int r = dd & 15;
            u32x2 t;
            t[0] = pk2bf(vreg[0][jj], vreg[1][jj]);
            t[1] = pk2bf(vreg[2][jj], vreg[3][jj]);
            *(u32x2*)(base + 8192 + f * 1024 + sigma_slot(r, vg, f) * 16 + 8 * vu) = t;
        }
    };

    const int nt = 2 * qt + 2;
    const int qb = qt * QBLK;
    const int qr = qb + 16 * w + lr;     // this lane's q row
    const int wqmin = qb + 16 * w;       // wave's min q-row (uniform)

    // Q fragments (B-operand), pre-scaled; k-map 8g+j matches K slot content
    s16x8 qf[4];
#pragma unroll
    for (int kk = 0; kk < 4; ++kk) {
        const float* qp = qbh + (size_t)qr * ROWSTR + kk * 32 + g * 8;
        f32x4 a = *(const f32x4*)qp, b = *(const f32x4*)(qp + 4);
        unsigned* tu = (unsigned*)&qf[kk];
        tu[0] = pk2bf(a[0] * QSCALE, a[1] * QSCALE);
        tu[1] = pk2bf(a[2] * QSCALE, a[3] * QSCALE);
        tu[2] = pk2bf(b[0] * QSCALE, b[1] * QSCALE);
        tu[3] = pk2bf(b[2] * QSCALE, b[3] * QSCALE);
    }

    f32x4 acc[8];
#pragma unroll
    for (int i = 0; i < 8; ++i) acc[i] = (f32x4){0.f, 0.f, 0.f, 0.f};
    float mrun = -INFINITY, lrun = 0.f;

    prefetch(0);
    stage(lds[0]);
    prefetch(KVBLK);
    __syncthreads();

    for (int t = 0; t < nt; ++t) {
        const int cur = t & 1;

        if (t + 1 < nt) {
            stage(lds[cur ^ 1]);                 // tile t+1 (regs ready)
            if (t + 2 < nt) prefetch((t + 2) * KVBLK);
        }

        const char* bK = lds[cur];
        const char* bV = lds[cur] + 8192;
        const int kv0 = t * KVBLK;

        if (kv0 <= wqmin + 15) {                 // wave-uniform causal skip
            // ---- S^T = K · Q^T : sa[m] reg r = S[kv0+16m+4g+r][q=qr]
            f32x4 sa[2];
            sa[0] = (f32x4){0.f, 0.f, 0.f, 0.f};
            sa[1] = (f32x4){0.f, 0.f, 0.f, 0.f};
            __builtin_amdgcn_s_setprio(1);
#pragma unroll
            for (int m = 0; m < 2; ++m)
#pragma unroll
                for (int kk = 0; kk < 4; ++kk) {
                    int f = 4 * m + kk;
                    s16x8 kf = *(const s16x8*)(bK + rbase[f] + f * 1024);
                    sa[m] = __builtin_amdgcn_mfma_f32_16x16x32_bf16(kf, qf[kk], sa[m], 0, 0, 0);
                }
            __builtin_amdgcn_s_setprio(0);

            float s_[8];
#pragma unroll
            for (int m = 0; m < 2; ++m)
#pragma unroll
                for (int r = 0; r < 4; ++r) s_[4 * m + r] = sa[m][r];

            if (kv0 + KVBLK - 1 > wqmin) {       // diagonal-region masking
#pragma unroll
                for (int m = 0; m < 2; ++m)
#pragma unroll
                    for (int r = 0; r < 4; ++r)
                        if (kv0 + 16 * m + 4 * g + r > qr) s_[4 * m + r] = -INFINITY;
            }

            float mx = s_[0];
#pragma unroll
            for (int i = 1; i < 8; ++i) mx = fmaxf(mx, s_[i]);
            mx = fmaxf(mx, __shfl_xor(mx, 16));
            mx = fmaxf(mx, __shfl_xor(mx, 32));

            if (!__all(mx - mrun <= 8.0f)) {     // defer-max rescale
                float mnew = fmaxf(mrun, mx);
                float corr = __builtin_amdgcn_exp2f(mrun - mnew);
                lrun *= corr;
#pragma unroll
                for (int db = 0; db < 8; ++db)
#pragma unroll
                    for (int r = 0; r < 4; ++r) acc[db][r] *= corr;
                mrun = mnew;
            }

            float ts = 0.f;
#pragma unroll
            for (int i = 0; i < 8; ++i) {
                float p = __builtin_amdgcn_exp2f(s_[i] - mrun);
                s_[i] = p;
                ts += p;
            }
            ts += __shfl_xor(ts, 16);
            ts += __shfl_xor(ts, 32);
            lrun += ts;

            // pack P: pa[j] = P[qr][kv0 + 16(j>>2)+4g+(j&3)] = s_[j]
            s16x8 pa;
            {
                unsigned* pu = (unsigned*)&pa;
#pragma unroll
                for (int jj = 0; jj < 4; ++jj)
                    pu[jj] = pk2bf(s_[2 * jj], s_[2 * jj + 1]);
            }

            // ---- O^T += V^T · P^T
            __builtin_amdgcn_s_setprio(1);
#pragma unroll
            for (int db = 0; db < 8; ++db) {
                s16x8 vf = *(const s16x8*)(bV + rbase[db] + db * 1024);
                acc[db] = __builtin_amdgcn_mfma_f32_16x16x32_bf16(vf, pa, acc[db], 0, 0, 0);
            }
            __builtin_amdgcn_s_setprio(0);
        }
        __syncthreads();
    }

    // ---- epilogue: lane holds O[qr][d = db*16 + 4g + r]
    float inv = 1.0f / lrun;
    float* op = out + (size_t)qr * ROWSTR + bh * DDIM;
#pragma unroll
    for (int db = 0; db < 8; ++db) {
        f32x4 o;
#pragma unroll
        for (int r = 0; r < 4; ++r) o[r] = acc[db][r] * inv;
        *(f32x4*)(op + db * 16 + g * 4) = o;
    }
}

extern "C" void kernel_launch(void* const* d_in, const int* in_sizes, int n_in,
                              void* d_out, int out_size, void* d_ws, size_t ws_size,
                              hipStream_t stream) {
    const float* q = (const float*)d_in[0];
    const float* k = (const float*)d_in[1];
    const float* v = (const float*)d_in[2];
    float* o = (float*)d_out;
    dim3 grid(32 * NQT);   // 1024 = 4 blocks/CU, all co-resident
    dim3 block(256);
    fattn_kernel<<<grid, block, 0, stream>>>(q, k, v, o);
}

// Round 7
// 86.416 us; speedup vs baseline: 1.2863x; 1.2863x over previous
//
#include <hip/hip_runtime.h>
#include <hip/hip_bf16.h>

// Fused causal attention, S=2048 B=2 H=16 D=128, sbhd, fp32 in/out, bf16 MFMA.
// Round 7 = round 3's balanced schedule (QBLK=64, KVBLK=64, paired q-tiles ->
// uniform 33 tiles/block, grid 512 = 2 blocks/CU, 1 barrier/tile) + round 4's
// fragment-linear conflict-free LDS (rbase, zero per-read VALU) + sched_barrier
// pin so the register prefetch actually issues one iteration early.

#define DDIM    128
#define ROWSTR  4096          // B*H*D element stride along s/t
#define QBLK    64
#define KVBLK   64
#define NQT     32            // 2048 / QBLK
#define QSCALE  0.1275174190023967f   // (1/sqrt(128)) * log2(e)

typedef __attribute__((ext_vector_type(4))) float f32x4;
typedef __attribute__((ext_vector_type(8))) short s16x8;

__device__ inline unsigned pk2bf(float a, float b) {
    union { __hip_bfloat162 h; unsigned u; } cv;
    cv.h = __float22bfloat162_rn(float2{a, b});
    return cv.u;
}

// LDS per buffer: K region 16KB (16 chunks of 1KB, f = 4m+kk) then V region
// 16KB (16 chunks, f = 2*db + kvhalf). Chunk slot sigma(r,g,f) =
// (r ^ ((g^phi)&3) ^ ((psi ^ (r>>3))<<2)) + 16g, phi=(f>>1)&3, psi=f&1.
// Reads: ds_read_b128 at rbase[f&7] + f*1024 (base VGPR + immediate only).

__device__ inline int sigma_slot(int r, int g, int f) {
    int phi = (f >> 1) & 3, psi = f & 1;
    return (r ^ ((g ^ phi) & 3) ^ ((psi ^ (r >> 3)) << 2)) + 16 * g;
}

__global__ __launch_bounds__(256, 2)
void fattn_kernel(const float* __restrict__ q, const float* __restrict__ k,
                  const float* __restrict__ v, float* __restrict__ out)
{
    __shared__ char lds[2][32768];   // [buf][ K 16KB | V 16KB ]

    const int tid = threadIdx.x;
    const int w = tid >> 6, l = tid & 63, g = l >> 4, lr = l & 15;
    const int bid = blockIdx.x;
    const int bh = bid & 31;          // same-head blocks share an XCD (32%8==0)
    const int pr = bid >> 5;          // 0..15 pair index

    const float* qbh = q + bh * DDIM;
    const float* kbh = k + bh * DDIM;
    const float* vbh = v + bh * DDIM;

    // ---- 8 read bases (per f&7), computed once
    int rbase[8];
#pragma unroll
    for (int f = 0; f < 8; ++f) rbase[f] = sigma_slot(lr, g, f) * 16;

    // staging maps
    const int krow0 = tid >> 4;          // K: r (0..15), rows krow0+16m
    const int kc    = tid & 15;          // K: d cols 8*kc..; kk=kc>>2, g'=kc&3
    const int kk2   = kc >> 2, kg = kc & 3;
    const int vq4   = tid & 31;          // V: d quad (dd = 4*vq4+jj)
    const int vc    = tid >> 5;          // V: kv slot
    const int vhalf = vc >> 2, vg = vc & 3;

    f32x4 kreg[8], vreg[8];

    auto prefetch = [&](int kv0) {
        const float* kp = kbh + (size_t)(kv0 + krow0) * ROWSTR + kc * 8;
#pragma unroll
        for (int m = 0; m < 4; ++m) {
            kreg[2 * m]     = *(const f32x4*)(kp + (size_t)(16 * m) * ROWSTR);
            kreg[2 * m + 1] = *(const f32x4*)(kp + (size_t)(16 * m) * ROWSTR + 4);
        }
        const float* vp = vbh + (size_t)(kv0 + 32 * vhalf + 4 * vg) * ROWSTR + vq4 * 4;
#pragma unroll
        for (int i = 0; i < 4; ++i) {
            vreg[i]     = *(const f32x4*)(vp + (size_t)i * ROWSTR);
            vreg[4 + i] = *(const f32x4*)(vp + (size_t)(16 + i) * ROWSTR);
        }
    };

    auto stage = [&](char* base) {
#pragma unroll
        for (int m = 0; m < 4; ++m) {
            int f = 4 * m + kk2;
            s16x8 t; unsigned* tu = (unsigned*)&t;
            tu[0] = pk2bf(kreg[2 * m][0],     kreg[2 * m][1]);
            tu[1] = pk2bf(kreg[2 * m][2],     kreg[2 * m][3]);
            tu[2] = pk2bf(kreg[2 * m + 1][0], kreg[2 * m + 1][1]);
            tu[3] = pk2bf(kreg[2 * m + 1][2], kreg[2 * m + 1][3]);
            *(s16x8*)(base + f * 1024 + sigma_slot(krow0, kg, f) * 16) = t;
        }
#pragma unroll
        for (int jj = 0; jj < 4; ++jj) {
            int dd = 4 * vq4 + jj;
            int f = (dd >> 4) * 2 + vhalf;
            int r = dd & 15;
            s16x8 t; unsigned* tu = (unsigned*)&t;
            tu[0] = pk2bf(vreg[0][jj], vreg[1][jj]);
            tu[1] = pk2bf(vreg[2][jj], vreg[3][jj]);
            tu[2] = pk2bf(vreg[4][jj], vreg[5][jj]);
            tu[3] = pk2bf(vreg[6][jj], vreg[7][jj]);
            *(s16x8*)(base + 16384 + f * 1024 + sigma_slot(r, vg, f) * 16) = t;
        }
    };

    const int qtA = pr, qtB = NQT - 1 - pr;
    const int ntA = pr + 1, ntB = NQT - pr;
    const int total = ntA + ntB;          // uniform 33

    int qb = qtA * QBLK;
    int qr = qb + 16 * w + lr;            // this lane's q row

    s16x8 qf[4];
    auto load_qf = [&]() {
#pragma unroll
        for (int kk = 0; kk < 4; ++kk) {
            const float* qp = qbh + (size_t)qr * ROWSTR + kk * 32 + g * 8;
            f32x4 a = *(const f32x4*)qp, b = *(const f32x4*)(qp + 4);
            unsigned* tu = (unsigned*)&qf[kk];
            tu[0] = pk2bf(a[0] * QSCALE, a[1] * QSCALE);
            tu[1] = pk2bf(a[2] * QSCALE, a[3] * QSCALE);
            tu[2] = pk2bf(b[0] * QSCALE, b[1] * QSCALE);
            tu[3] = pk2bf(b[2] * QSCALE, b[3] * QSCALE);
        }
    };
    load_qf();

    f32x4 acc[8];
#pragma unroll
    for (int i = 0; i < 8; ++i) acc[i] = (f32x4){0.f, 0.f, 0.f, 0.f};
    float mrun = -INFINITY, lrun = 0.f;

    auto kv_of = [&](int tt) { return (tt < ntA ? tt : tt - ntA) * KVBLK; };

    prefetch(0);
    __builtin_amdgcn_sched_barrier(0);
    stage(lds[0]);
    prefetch(kv_of(1));
    __builtin_amdgcn_sched_barrier(0);    // pin the loads here (issue-early)
    __syncthreads();

    for (int tt = 0; tt < total; ++tt) {
        const int cur = tt & 1;
        const bool phB = tt >= ntA;
        const int t  = phB ? tt - ntA : tt;
        const int nt = phB ? ntB : ntA;

        if (tt + 1 < total) {
            stage(lds[cur ^ 1]);          // consume regs loaded last iteration
            if (tt + 2 < total) prefetch(kv_of(tt + 2));
            __builtin_amdgcn_sched_barrier(0);  // loads must issue before compute
        }

        const char* bK = lds[cur];
        const char* bV = lds[cur] + 16384;
        const int kv0 = t * KVBLK;

        // ---- S^T = K · Q^T : sa[m] reg r = S[kv0+16m+4g+r][q=qr]
        f32x4 sa[4];
#pragma unroll
        for (int m = 0; m < 4; ++m) sa[m] = (f32x4){0.f, 0.f, 0.f, 0.f};
        __builtin_amdgcn_s_setprio(1);
#pragma unroll
        for (int m = 0; m < 4; ++m)
#pragma unroll
            for (int kk = 0; kk < 4; ++kk) {
                int f = 4 * m + kk;
                s16x8 kf = *(const s16x8*)(bK + rbase[f & 7] + f * 1024);
                sa[m] = __builtin_amdgcn_mfma_f32_16x16x32_bf16(kf, qf[kk], sa[m], 0, 0, 0);
            }
        __builtin_amdgcn_s_setprio(0);

        float s_[16];
#pragma unroll
        for (int m = 0; m < 4; ++m)
#pragma unroll
            for (int r = 0; r < 4; ++r) s_[4 * m + r] = sa[m][r];

        if (t == nt - 1) {                // diagonal tile only
#pragma unroll
            for (int m = 0; m < 4; ++m)
#pragma unroll
                for (int r = 0; r < 4; ++r)
                    if (kv0 + 16 * m + 4 * g + r > qr) s_[4 * m + r] = -INFINITY;
        }

        float mx = s_[0];
#pragma unroll
        for (int i = 1; i < 16; ++i) mx = fmaxf(mx, s_[i]);
        mx = fmaxf(mx, __shfl_xor(mx, 16));
        mx = fmaxf(mx, __shfl_xor(mx, 32));

        if (!__all(mx - mrun <= 8.0f)) {  // defer-max rescale (2^8 headroom)
            float mnew = fmaxf(mrun, mx);
            float corr = __builtin_amdgcn_exp2f(mrun - mnew);
            lrun *= corr;
#pragma unroll
            for (int db = 0; db < 8; ++db)
#pragma unroll
                for (int r = 0; r < 4; ++r) acc[db][r] *= corr;
            mrun = mnew;
        }

        float ts = 0.f;
#pragma unroll
        for (int i = 0; i < 16; ++i) {
            float p = __builtin_amdgcn_exp2f(s_[i] - mrun);
            s_[i] = p;
            ts += p;
        }
        ts += __shfl_xor(ts, 16);
        ts += __shfl_xor(ts, 32);
        lrun += ts;

        // pack P: pa[hf] element (g,j) = P[qr][kv0+32hf+16(j>>2)+4g+(j&3)] = s_[8hf+j]
        s16x8 pa[2];
#pragma unroll
        for (int hf = 0; hf < 2; ++hf) {
            unsigned* pu = (unsigned*)&pa[hf];
#pragma unroll
            for (int jj = 0; jj < 4; ++jj)
                pu[jj] = pk2bf(s_[8 * hf + 2 * jj], s_[8 * hf + 2 * jj + 1]);
        }

        // ---- O^T += V^T · P^T
        __builtin_amdgcn_s_setprio(1);
#pragma unroll
        for (int db = 0; db < 8; ++db)
#pragma unroll
            for (int hf = 0; hf < 2; ++hf) {
                int f = 2 * db + hf;
                s16x8 vf = *(const s16x8*)(bV + rbase[f & 7] + f * 1024);
                acc[db] = __builtin_amdgcn_mfma_f32_16x16x32_bf16(vf, pa[hf], acc[db], 0, 0, 0);
            }
        __builtin_amdgcn_s_setprio(0);

        if (t == nt - 1) {
            // ---- epilogue: lane holds O[qr][d = db*16 + 4g + r]
            float inv = 1.0f / lrun;
            float* op = out + (size_t)qr * ROWSTR + bh * DDIM;
#pragma unroll
            for (int db = 0; db < 8; ++db) {
                f32x4 o;
#pragma unroll
                for (int r = 0; r < 4; ++r) o[r] = acc[db][r] * inv;
                *(f32x4*)(op + db * 16 + g * 4) = o;
            }
            if (!phB) {                   // reset context for phase B
#pragma unroll
                for (int i = 0; i < 8; ++i) acc[i] = (f32x4){0.f, 0.f, 0.f, 0.f};
                mrun = -INFINITY; lrun = 0.f;
                qb = qtB * QBLK;
                qr = qb + 16 * w + lr;
                load_qf();
            }
        }
        __syncthreads();
    }
}

extern "C" void kernel_launch(void* const* d_in, const int* in_sizes, int n_in,
                              void* d_out, int out_size, void* d_ws, size_t ws_size,
                              hipStream_t stream) {
    const float* q = (const float*)d_in[0];
    const float* k = (const float*)d_in[1];
    const float* v = (const float*)d_in[2];
    float* o = (float*)d_out;
    dim3 grid(32 * 16);   // 512 blocks = 2/CU, all co-resident, uniform work
    dim3 block(256);
    fattn_kernel<<<grid, block, 0, stream>>>(q, k, v, o);
}